// Round 1
// baseline (8621.581 us; speedup 1.0000x reference)
//
#include <hip/hip_runtime.h>
#include <cstddef>

#define F 128
#define H 512
#define RB 32          // rows per block
#define NSTEPS 100
#define W1S 136        // W1t / abuf row stride (elements, 16B-aligned, bank-safe)
#define HS  520        // h buffer row stride (elements, 16B-aligned, bank-safe)

typedef short short8 __attribute__((ext_vector_type(8)));
typedef float f32x4  __attribute__((ext_vector_type(4)));

__device__ __forceinline__ unsigned short f2bf(float f) {
    union { float f; unsigned int u; } v; v.f = f;
    unsigned int u = v.u;
    return (unsigned short)((u + 0x7FFFu + ((u >> 16) & 1u)) >> 16);  // RTNE
}
__device__ __forceinline__ float bf2f(unsigned short h) {
    union { unsigned int u; float f; } v; v.u = ((unsigned int)h) << 16;
    return v.f;
}
__device__ __forceinline__ float silu_f(float v) {
    float e = __expf(-v);
    return v * __builtin_amdgcn_rcpf(1.0f + e);
}

// ---- prep: transpose weights to bf16 B^T layout in workspace -------------
// ws layout (unsigned short elements):
//   W1t [512][136] : W1t[n][k] = W1[k][n], k<129 (k=128 is the t-column)
//   W2t [512][512] : W2t[n][k] = W2[k][n]
//   W3t [128][512] : W3t[c][k] = W3[k][c]
__global__ void prep_weights(const float* __restrict__ W1,
                             const float* __restrict__ W2,
                             const float* __restrict__ W3,
                             unsigned short* __restrict__ ws) {
    unsigned short* W1t = ws;
    unsigned short* W2t = ws + 512 * W1S;
    unsigned short* W3t = W2t + 512 * 512;
    int stride = gridDim.x * blockDim.x;
    int t0 = blockIdx.x * blockDim.x + threadIdx.x;
    for (int i = t0; i < 512 * W1S; i += stride) {
        int n = i / W1S, k = i - n * W1S;
        W1t[i] = (k < 129) ? f2bf(W1[k * 512 + n]) : (unsigned short)0;
    }
    for (int i = t0; i < 512 * 512; i += stride) {
        int n = i >> 9, k = i & 511;
        W2t[i] = f2bf(W2[k * 512 + n]);
    }
    for (int i = t0; i < 128 * 512; i += stride) {
        int c = i >> 9, k = i & 511;
        W3t[i] = f2bf(W3[k * 128 + c]);
    }
}

// ---- main persistent kernel: one block = 32 batch rows, full trajectory --
__global__ __launch_bounds__(512, 2) void ode_kernel(
    const float* __restrict__ x_in,
    const float* __restrict__ b1,
    const float* __restrict__ b2,
    const float* __restrict__ b3,
    const unsigned short* __restrict__ ws,
    float* __restrict__ traj) {

    __shared__ __attribute__((aligned(16))) unsigned short abuf[RB * W1S]; // bf16 GEMM-A input
    __shared__ __attribute__((aligned(16))) unsigned short hbuf[RB * HS];  // h1 then h2 (bf16)

    const unsigned short* W1t = ws;
    const unsigned short* W2t = ws + 512 * W1S;
    const unsigned short* W3t = W2t + 512 * 512;

    const int tid  = threadIdx.x;
    const int wave = tid >> 6;          // 0..7
    const int lane = tid & 63;
    const int l15  = lane & 15;
    const int q    = lane >> 4;         // quad 0..3
    const int rowbase = blockIdx.x * RB;

    // column this thread owns in layer3 / elementwise (MFMA C-layout: col = lane&15)
    const int cown = wave * 16 + l15;
    const float bias3 = b3[cown];

    float xreg[8];    // RK4 state, owner-lane resident: rows mt*16+q*4+i, col cown
    float accreg[8];  // RK4 accumulator

    // phase 0: load x, emit traj[0], fill abuf = bf16(x)
#pragma unroll
    for (int mt = 0; mt < 2; ++mt)
#pragma unroll
        for (int i = 0; i < 4; ++i) {
            int r = mt * 16 + q * 4 + i;
            float v = x_in[(rowbase + r) * F + cown];
            xreg[mt * 4 + i] = v;
            traj[(rowbase + r) * F + cown] = v;
            abuf[r * W1S + cown] = f2bf(v);
        }
    __syncthreads();

#pragma unroll 1
    for (int s = 0; s < NSTEPS - 1; ++s) {
        const float t0  = (float)s * (1.0f / 99.0f);
        const float tn  = (float)(s + 1) * (1.0f / 99.0f);
        const float dt  = tn - t0;
        const float hlf = 0.5f * dt;
        const float c16 = dt * (1.0f / 6.0f);
        const float c13 = dt * (1.0f / 3.0f);

#pragma unroll 1
        for (int e = 0; e < 4; ++e) {
            const float te = (e == 0) ? t0 : ((e == 3) ? tn : (t0 + hlf));

            // ---- layer 1: h1 = silu([x,t] @ W1 + b1), K=128 (+ t column)
#pragma unroll
            for (int nt = 0; nt < 4; ++nt) {
                const int n = (wave * 4 + nt) * 16 + l15;
                const unsigned short* wrow = W1t + n * W1S;
                f32x4 a0 = {0.f, 0.f, 0.f, 0.f};
                f32x4 a1 = {0.f, 0.f, 0.f, 0.f};
#pragma unroll
                for (int kt = 0; kt < 4; ++kt) {
                    short8 bf  = *(const short8*)(wrow + kt * 32 + q * 8);
                    short8 af0 = *(const short8*)(abuf + l15 * W1S + kt * 32 + q * 8);
                    short8 af1 = *(const short8*)(abuf + (16 + l15) * W1S + kt * 32 + q * 8);
                    a0 = __builtin_amdgcn_mfma_f32_16x16x32_bf16(af0, bf, a0, 0, 0, 0);
                    a1 = __builtin_amdgcn_mfma_f32_16x16x32_bf16(af1, bf, a1, 0, 0, 0);
                }
                const float bb = b1[n] + te * bf2f(wrow[128]);
#pragma unroll
                for (int i = 0; i < 4; ++i) {
                    int m = q * 4 + i;
                    hbuf[m * HS + n]        = f2bf(silu_f(a0[i] + bb));
                    hbuf[(m + 16) * HS + n] = f2bf(silu_f(a1[i] + bb));
                }
            }
            __syncthreads();

            // ---- layer 2: acc2 = h1 @ W2 (K=512), fully in registers
            f32x4 zero4 = {0.f, 0.f, 0.f, 0.f};
            f32x4 acc2[4][2];
#pragma unroll
            for (int nt = 0; nt < 4; ++nt) { acc2[nt][0] = zero4; acc2[nt][1] = zero4; }

#pragma unroll 4
            for (int kt = 0; kt < 16; ++kt) {
                short8 af0 = *(const short8*)(hbuf + l15 * HS + kt * 32 + q * 8);
                short8 af1 = *(const short8*)(hbuf + (16 + l15) * HS + kt * 32 + q * 8);
#pragma unroll
                for (int nt = 0; nt < 4; ++nt) {
                    const int n = (wave * 4 + nt) * 16 + l15;
                    short8 bf = *(const short8*)(W2t + n * 512 + kt * 32 + q * 8);
                    acc2[nt][0] = __builtin_amdgcn_mfma_f32_16x16x32_bf16(af0, bf, acc2[nt][0], 0, 0, 0);
                    acc2[nt][1] = __builtin_amdgcn_mfma_f32_16x16x32_bf16(af1, bf, acc2[nt][1], 0, 0, 0);
                }
            }
            __syncthreads();   // everyone done READING h1 before overwrite

            // write h2 = silu(acc2 + b2) over hbuf
#pragma unroll
            for (int nt = 0; nt < 4; ++nt) {
                const int n = (wave * 4 + nt) * 16 + l15;
                const float bb = b2[n];
#pragma unroll
                for (int i = 0; i < 4; ++i) {
                    int m = q * 4 + i;
                    hbuf[m * HS + n]        = f2bf(silu_f(acc2[nt][0][i] + bb));
                    hbuf[(m + 16) * HS + n] = f2bf(silu_f(acc2[nt][1][i] + bb));
                }
            }
            __syncthreads();

            // ---- layer 3: k = h2 @ W3 + b3 (K=512), then RK4 elementwise
            {
                const unsigned short* wrow = W3t + cown * 512;
                f32x4 a0 = {0.f, 0.f, 0.f, 0.f};
                f32x4 a1 = {0.f, 0.f, 0.f, 0.f};
#pragma unroll 4
                for (int kt = 0; kt < 16; ++kt) {
                    short8 bf  = *(const short8*)(wrow + kt * 32 + q * 8);
                    short8 af0 = *(const short8*)(hbuf + l15 * HS + kt * 32 + q * 8);
                    short8 af1 = *(const short8*)(hbuf + (16 + l15) * HS + kt * 32 + q * 8);
                    a0 = __builtin_amdgcn_mfma_f32_16x16x32_bf16(af0, bf, a0, 0, 0, 0);
                    a1 = __builtin_amdgcn_mfma_f32_16x16x32_bf16(af1, bf, a1, 0, 0, 0);
                }
#pragma unroll
                for (int mt = 0; mt < 2; ++mt) {
#pragma unroll
                    for (int i = 0; i < 4; ++i) {
                        const int r = mt * 16 + q * 4 + i;
                        const int j = mt * 4 + i;
                        const float kv = (mt ? a1[i] : a0[i]) + bias3;
                        if (e == 0) {
                            accreg[j] = xreg[j] + c16 * kv;
                            abuf[r * W1S + cown] = f2bf(xreg[j] + hlf * kv);
                        } else if (e == 1) {
                            accreg[j] += c13 * kv;
                            abuf[r * W1S + cown] = f2bf(xreg[j] + hlf * kv);
                        } else if (e == 2) {
                            accreg[j] += c13 * kv;
                            abuf[r * W1S + cown] = f2bf(xreg[j] + dt * kv);
                        } else {
                            float xn = accreg[j] + c16 * kv;
                            xreg[j] = xn;
                            abuf[r * W1S + cown] = f2bf(xn);
                            traj[(size_t)(s + 1) * (4096 * F) + (rowbase + r) * F + cown] = xn;
                        }
                    }
                }
            }
            __syncthreads();   // abuf ready for next eval's layer 1
        }
    }
}

extern "C" void kernel_launch(void* const* d_in, const int* in_sizes, int n_in,
                              void* d_out, int out_size, void* d_ws, size_t ws_size,
                              hipStream_t stream) {
    const float* x  = (const float*)d_in[0];
    const float* W1 = (const float*)d_in[1];
    const float* b1 = (const float*)d_in[2];
    const float* W2 = (const float*)d_in[3];
    const float* b2 = (const float*)d_in[4];
    const float* W3 = (const float*)d_in[5];
    const float* b3 = (const float*)d_in[6];
    // d_in[7] = n_steps (fixed at 100 per reference; hardcoded)

    unsigned short* wt = (unsigned short*)d_ws;  // needs 794,624 B
    float* traj = (float*)d_out;

    prep_weights<<<256, 256, 0, stream>>>(W1, W2, W3, wt);
    ode_kernel<<<4096 / RB, 512, 0, stream>>>(x, b1, b2, b3, wt, traj);
}

// Round 2
// 7668.024 us; speedup vs baseline: 1.1244x; 1.1244x over previous
//
#include <hip/hip_runtime.h>
#include <cstddef>

#define F 128
#define H 512
#define RB 16          // rows per block -> grid = 256 (one block per CU)
#define NSTEPS 100
#define W1S 136        // W1t row stride (elements, 16B-aligned)
#define ABS 136        // abuf row stride
#define HS  520        // h buffer row stride (16B-aligned, (l15+q)%8 spread)

typedef short short8 __attribute__((ext_vector_type(8)));
typedef float f32x4  __attribute__((ext_vector_type(4)));

__device__ __forceinline__ unsigned short f2bf(float f) {
    union { float f; unsigned int u; } v; v.f = f;
    unsigned int u = v.u;
    return (unsigned short)((u + 0x7FFFu + ((u >> 16) & 1u)) >> 16);  // RTNE
}
__device__ __forceinline__ float bf2f(unsigned short h) {
    union { unsigned int u; float f; } v; v.u = ((unsigned int)h) << 16;
    return v.f;
}
__device__ __forceinline__ float silu_f(float v) {
    float e = __expf(-v);
    return v * __builtin_amdgcn_rcpf(1.0f + e);
}

// ---- prep: transpose weights to bf16 B^T layout in workspace -------------
// ws layout (unsigned short elements):
//   W1t [512][136] : W1t[n][k] = W1[k][n], k<129 (k=128 is the t-column)
//   W2t [512][512] : W2t[n][k] = W2[k][n]
//   W3t [128][512] : W3t[c][k] = W3[k][c]
__global__ void prep_weights(const float* __restrict__ W1,
                             const float* __restrict__ W2,
                             const float* __restrict__ W3,
                             unsigned short* __restrict__ ws) {
    unsigned short* W1t = ws;
    unsigned short* W2t = ws + 512 * W1S;
    unsigned short* W3t = W2t + 512 * 512;
    int stride = gridDim.x * blockDim.x;
    int t0 = blockIdx.x * blockDim.x + threadIdx.x;
    for (int i = t0; i < 512 * W1S; i += stride) {
        int n = i / W1S, k = i - n * W1S;
        W1t[i] = (k < 129) ? f2bf(W1[k * 512 + n]) : (unsigned short)0;
    }
    for (int i = t0; i < 512 * 512; i += stride) {
        int n = i >> 9, k = i & 511;
        W2t[i] = f2bf(W2[k * 512 + n]);
    }
    for (int i = t0; i < 128 * 512; i += stride) {
        int c = i >> 9, k = i & 511;
        W3t[i] = f2bf(W3[k * 128 + c]);
    }
}

// ---- main persistent kernel: one block = 16 batch rows, full trajectory --
// 512 threads = 8 waves. Wave w owns h-columns [w*64, w*64+64) in layers 1/2
// and output columns [w*16, w*16+16) in layer 3. Single m-tile (M=16).
// W1/W3 fragments + biases preloaded to registers (constant across evals);
// only W2 streams from L2 each eval (512 KB/block/eval).
__global__ __launch_bounds__(512, 2) void ode_kernel(
    const float* __restrict__ x_in,
    const float* __restrict__ b1,
    const float* __restrict__ b2,
    const float* __restrict__ b3,
    const unsigned short* __restrict__ ws,
    float* __restrict__ traj) {

    __shared__ __attribute__((aligned(16))) unsigned short abuf[RB * ABS];  // bf16 state
    __shared__ __attribute__((aligned(16))) unsigned short h1buf[RB * HS];
    __shared__ __attribute__((aligned(16))) unsigned short h2buf[RB * HS];

    const unsigned short* W1t = ws;
    const unsigned short* W2t = ws + 512 * W1S;
    const unsigned short* W3t = W2t + 512 * 512;

    const int tid  = threadIdx.x;
    const int wave = tid >> 6;          // 0..7
    const int lane = tid & 63;
    const int l15  = lane & 15;
    const int q    = lane >> 4;         // quad 0..3
    const int rowbase = blockIdx.x * RB;

    // ---- preload constant weight fragments ----
    const int ncol = wave * 64 + l15;   // layer1/2 n-col base for nt=0
    short8 w1f[4][4];
    float  b1v[4], t1v[4], b2v[4];
#pragma unroll
    for (int nt = 0; nt < 4; ++nt) {
        const unsigned short* wrow = W1t + (ncol + nt * 16) * W1S;
#pragma unroll
        for (int kt = 0; kt < 4; ++kt)
            w1f[nt][kt] = *(const short8*)(wrow + kt * 32 + q * 8);
        t1v[nt] = bf2f(wrow[128]);
        b1v[nt] = b1[ncol + nt * 16];
        b2v[nt] = b2[ncol + nt * 16];
    }
    const int cown = wave * 16 + l15;   // layer-3 output column
    short8 w3f[16];
    {
        const unsigned short* wrow = W3t + cown * 512;
#pragma unroll
        for (int kt = 0; kt < 16; ++kt)
            w3f[kt] = *(const short8*)(wrow + kt * 32 + q * 8);
    }
    const float b3v = b3[cown];
    const unsigned short* w2base = W2t + (size_t)ncol * 512 + q * 8;

    float xreg[4];    // RK4 state: row q*4+i, col cown
    float accreg[4];

    // phase 0: load x, emit traj[0], fill abuf
#pragma unroll
    for (int i = 0; i < 4; ++i) {
        int r = q * 4 + i;
        float v = x_in[(rowbase + r) * F + cown];
        xreg[i] = v;
        traj[(rowbase + r) * F + cown] = v;
        abuf[r * ABS + cown] = f2bf(v);
    }
    __syncthreads();

#pragma unroll 1
    for (int s = 0; s < NSTEPS - 1; ++s) {
        const float t0  = (float)s * (1.0f / 99.0f);
        const float tn  = (float)(s + 1) * (1.0f / 99.0f);
        const float dt  = tn - t0;
        const float hlf = 0.5f * dt;
        const float c16 = dt * (1.0f / 6.0f);
        const float c13 = dt * (1.0f / 3.0f);

#pragma unroll 1
        for (int e = 0; e < 4; ++e) {
            const float te = (e == 0) ? t0 : ((e == 3) ? tn : (t0 + hlf));

            // ---- layer 1: h1 = silu([x,t] @ W1 + b1), K=128, weights in regs
            {
                short8 af[4];
#pragma unroll
                for (int kt = 0; kt < 4; ++kt)
                    af[kt] = *(const short8*)(abuf + l15 * ABS + kt * 32 + q * 8);
#pragma unroll
                for (int nt = 0; nt < 4; ++nt) {
                    f32x4 a = {0.f, 0.f, 0.f, 0.f};
#pragma unroll
                    for (int kt = 0; kt < 4; ++kt)
                        a = __builtin_amdgcn_mfma_f32_16x16x32_bf16(af[kt], w1f[nt][kt], a, 0, 0, 0);
                    const float bb = b1v[nt] + te * t1v[nt];
                    const int n = ncol + nt * 16;
#pragma unroll
                    for (int i = 0; i < 4; ++i)
                        h1buf[(q * 4 + i) * HS + n] = f2bf(silu_f(a[i] + bb));
                }
            }
            __syncthreads();

            // ---- layer 2: h2 = silu(h1 @ W2 + b2), K=512, W2 streamed from L2
            {
                f32x4 acc2[4];
#pragma unroll
                for (int nt = 0; nt < 4; ++nt) acc2[nt] = (f32x4){0.f, 0.f, 0.f, 0.f};

#pragma unroll
                for (int g = 0; g < 8; ++g) {
                    short8 bfr[2][4];
                    short8 af2[2];
#pragma unroll
                    for (int j = 0; j < 2; ++j) {
                        const int kt = g * 2 + j;
#pragma unroll
                        for (int nt = 0; nt < 4; ++nt)
                            bfr[j][nt] = *(const short8*)(w2base + (size_t)nt * (16 * 512) + kt * 32);
                        af2[j] = *(const short8*)(h1buf + l15 * HS + kt * 32 + q * 8);
                    }
#pragma unroll
                    for (int j = 0; j < 2; ++j)
#pragma unroll
                        for (int nt = 0; nt < 4; ++nt)
                            acc2[nt] = __builtin_amdgcn_mfma_f32_16x16x32_bf16(af2[j], bfr[j][nt], acc2[nt], 0, 0, 0);
                }
#pragma unroll
                for (int nt = 0; nt < 4; ++nt) {
                    const int n = ncol + nt * 16;
#pragma unroll
                    for (int i = 0; i < 4; ++i)
                        h2buf[(q * 4 + i) * HS + n] = f2bf(silu_f(acc2[nt][i] + b2v[nt]));
                }
            }
            __syncthreads();

            // ---- layer 3: k = h2 @ W3 + b3 (weights in regs), then RK4
            {
                f32x4 a3 = {0.f, 0.f, 0.f, 0.f};
#pragma unroll
                for (int kt = 0; kt < 16; ++kt) {
                    short8 af = *(const short8*)(h2buf + l15 * HS + kt * 32 + q * 8);
                    a3 = __builtin_amdgcn_mfma_f32_16x16x32_bf16(af, w3f[kt], a3, 0, 0, 0);
                }
#pragma unroll
                for (int i = 0; i < 4; ++i) {
                    const int r = q * 4 + i;
                    const float kv = a3[i] + b3v;
                    if (e == 0) {
                        accreg[i] = xreg[i] + c16 * kv;
                        abuf[r * ABS + cown] = f2bf(xreg[i] + hlf * kv);
                    } else if (e == 1) {
                        accreg[i] += c13 * kv;
                        abuf[r * ABS + cown] = f2bf(xreg[i] + hlf * kv);
                    } else if (e == 2) {
                        accreg[i] += c13 * kv;
                        abuf[r * ABS + cown] = f2bf(xreg[i] + dt * kv);
                    } else {
                        float xn = accreg[i] + c16 * kv;
                        xreg[i] = xn;
                        abuf[r * ABS + cown] = f2bf(xn);
                        traj[(size_t)(s + 1) * (4096 * F) + (rowbase + r) * F + cown] = xn;
                    }
                }
            }
            __syncthreads();
        }
    }
}

extern "C" void kernel_launch(void* const* d_in, const int* in_sizes, int n_in,
                              void* d_out, int out_size, void* d_ws, size_t ws_size,
                              hipStream_t stream) {
    const float* x  = (const float*)d_in[0];
    const float* W1 = (const float*)d_in[1];
    const float* b1 = (const float*)d_in[2];
    const float* W2 = (const float*)d_in[3];
    const float* b2 = (const float*)d_in[4];
    const float* W3 = (const float*)d_in[5];
    const float* b3 = (const float*)d_in[6];
    // d_in[7] = n_steps (fixed at 100 per reference; hardcoded)

    unsigned short* wt = (unsigned short*)d_ws;  // needs 794,624 B
    float* traj = (float*)d_out;

    prep_weights<<<256, 256, 0, stream>>>(W1, W2, W3, wt);
    ode_kernel<<<4096 / RB, 512, 0, stream>>>(x, b1, b2, b3, wt, traj);
}